// Round 3
// baseline (369.778 us; speedup 1.0000x reference)
//
#include <hip/hip_runtime.h>
#include <cstdint>

#define NPATH 131072
#define TPTS  500
#define NSTEP (TPTS - 1)
#define HID   64
#define BLOCK 256

// K = 2*log2(e): tanh(a) = 1 - 2 / (2^(K*a) + 1)   (exact identity)
#define K2LOG2E 2.8853900817779268f

__device__ __forceinline__ float fexp2(float x) { return __builtin_amdgcn_exp2f(x); }
__device__ __forceinline__ float frcp(float x)  { return __builtin_amdgcn_rcpf(x); }

// One Euler-Maruyama step, fast path: exactly one active (w1 != 0) term per MLP.
// Pre-transformed scalars:
//   w1p = K*w1, b1p = K*b1, w2t = -2*K*w2, D = K*(csum + b2 + asum)
// where csum = sum_{inactive j} w2[j]*tanh(b1[j]), asum = sum_{active j} w2[j].
// chain: e = 2^(w1p*y + b1p); r = 1/(e+1); acc = w2t*r + D; out = 1 - 2/(2^acc + 1)
__device__ __forceinline__ float sde_step(float y, float dt, float sdt, float z,
                                          float fw1, float fb1, float fw2, float fD,
                                          float gw1, float gb1, float gw2, float gD)
{
    float zdt = sdt * z;                       // off the critical y-chain
    // drift MLP
    float ef  = fexp2(fmaf(fw1, y, fb1));
    float rf  = frcp(ef + 1.0f);
    float af  = fmaf(fw2, rf, fD);
    float r2f = frcp(fexp2(af) + 1.0f);
    float fv  = fmaf(-2.0f, r2f, 1.0f);
    // diffusion MLP
    float eg  = fexp2(fmaf(gw1, y, gb1));
    float rg  = frcp(eg + 1.0f);
    float ag  = fmaf(gw2, rg, gD);
    float r2g = frcp(fexp2(ag) + 1.0f);
    float gv  = fmaf(-2.0f, r2g, 1.0f);

    y = fmaf(fv, dt, y);
    return fmaf(gv, zdt, y);
}

__global__ __launch_bounds__(BLOCK) void deepsde_kernel(
    const float* __restrict__ y0,
    const float* __restrict__ times,
    const float* __restrict__ noise,
    const float* __restrict__ f1_w, const float* __restrict__ f1_b,
    const float* __restrict__ f2_w, const float* __restrict__ f2_b,
    const float* __restrict__ g1_w, const float* __restrict__ g1_b,
    const float* __restrict__ g2_w, const float* __restrict__ g2_b,
    float* __restrict__ out)
{
    __shared__ float2 s_dt[NSTEP];          // (dt, sqrt(dt)) per step  (~4 KB)
    __shared__ float  s_w1p[2][HID], s_b1p[2][HID], s_w2t[2][HID];
    __shared__ float  s_D[2];
    __shared__ int    s_n[2];

    const int tid = threadIdx.x;

    // dt table into LDS (uniform across blocks; times is 500 floats, L2-hot)
    for (int t = tid; t < NSTEP; t += BLOCK) {
        float dt = times[t + 1] - times[t];
        s_dt[t] = make_float2(dt, sqrtf(dt));
    }

    // Weight preprocessing: wave 0 -> f-MLP, wave 1 -> g-MLP.
    // Fold all w1==0 terms into a constant; keep active terms (pre-scaled by K).
    if (tid < 128) {
        const int which = tid >> 6;   // 0=f, 1=g
        const int lane  = tid & 63;
        const float* w1 = which ? g1_w : f1_w;
        const float* b1 = which ? g1_b : f1_b;
        const float* w2 = which ? g2_w : f2_w;
        const float* b2 = which ? g2_b : f2_b;
        float w1v = w1[lane];
        float b1v = b1[lane];
        float w2v = w2[lane];
        bool active = (w1v != 0.0f);
        unsigned long long mask = __ballot(active);
        float csum = active ? 0.0f : w2v * tanhf(b1v);   // constant contribution
        float asum = active ? w2v : 0.0f;                // sum of active w2
        for (int off = 32; off > 0; off >>= 1) {
            csum += __shfl_down(csum, off);
            asum += __shfl_down(asum, off);
        }
        if (lane == 0) {
            s_n[which] = __popcll(mask);
            s_D[which] = K2LOG2E * (csum + b2[0] + asum);
        }
        if (active) {
            int rank = __popcll(mask & ((1ull << lane) - 1ull));
            s_w1p[which][rank] = K2LOG2E * w1v;
            s_b1p[which][rank] = K2LOG2E * b1v;
            s_w2t[which][rank] = -2.0f * K2LOG2E * w2v;
        }
    }
    __syncthreads();

    const int i = blockIdx.x * BLOCK + tid;
    const int nf = s_n[0], ng = s_n[1];
    const float fD = s_D[0], gD = s_D[1];

    float y = y0[i];
    const float yinit = y;

    if (nf == 1 && ng == 1) {
        // ---- fast path: single active term per MLP (the given inputs) ----
        const float fw1 = s_w1p[0][0], fb1 = s_b1p[0][0], fw2 = s_w2t[0][0];
        const float gw1 = s_w1p[1][0], gb1 = s_b1p[1][0], gw2 = s_w2t[1][0];

        const float* np = noise + i;

        // 8-deep register prefetch: 2 waves/SIMD only, so latency hiding is all
        // ILP. 8 loads in flight/thread -> 4 KB in flight/SIMD ≈ 4.5 B/cy over
        // ~900 cy HBM latency, above the ~2.6 B/cy needed for 6.3 TB/s.
        float z0 = np[0 * NPATH];
        float z1 = np[1 * NPATH];
        float z2 = np[2 * NPATH];
        float z3 = np[3 * NPATH];
        float z4 = np[4 * NPATH];
        float z5 = np[5 * NPATH];
        float z6 = np[6 * NPATH];
        float z7 = np[7 * NPATH];

        int t = 0;
        for (; t + 15 < NSTEP; t += 8) {
            const float* pp = np + (size_t)(t + 8) * NPATH;
            float n0 = pp[0 * NPATH];
            float n1 = pp[1 * NPATH];
            float n2 = pp[2 * NPATH];
            float n3 = pp[3 * NPATH];
            float n4 = pp[4 * NPATH];
            float n5 = pp[5 * NPATH];
            float n6 = pp[6 * NPATH];
            float n7 = pp[7 * NPATH];
            float2 d0 = s_dt[t],     d1 = s_dt[t + 1], d2 = s_dt[t + 2], d3 = s_dt[t + 3];
            float2 d4 = s_dt[t + 4], d5 = s_dt[t + 5], d6 = s_dt[t + 6], d7 = s_dt[t + 7];
            y = sde_step(y, d0.x, d0.y, z0, fw1, fb1, fw2, fD, gw1, gb1, gw2, gD);
            y = sde_step(y, d1.x, d1.y, z1, fw1, fb1, fw2, fD, gw1, gb1, gw2, gD);
            y = sde_step(y, d2.x, d2.y, z2, fw1, fb1, fw2, fD, gw1, gb1, gw2, gD);
            y = sde_step(y, d3.x, d3.y, z3, fw1, fb1, fw2, fD, gw1, gb1, gw2, gD);
            y = sde_step(y, d4.x, d4.y, z4, fw1, fb1, fw2, fD, gw1, gb1, gw2, gD);
            y = sde_step(y, d5.x, d5.y, z5, fw1, fb1, fw2, fD, gw1, gb1, gw2, gD);
            y = sde_step(y, d6.x, d6.y, z6, fw1, fb1, fw2, fD, gw1, gb1, gw2, gD);
            y = sde_step(y, d7.x, d7.y, z7, fw1, fb1, fw2, fD, gw1, gb1, gw2, gD);
            z0 = n0; z1 = n1; z2 = n2; z3 = n3;
            z4 = n4; z5 = n5; z6 = n6; z7 = n7;
        }
        // loop exits with t == 488: 8 buffered steps (488..495), then 3 direct
        {
            float2 d0 = s_dt[t],     d1 = s_dt[t + 1], d2 = s_dt[t + 2], d3 = s_dt[t + 3];
            float2 d4 = s_dt[t + 4], d5 = s_dt[t + 5], d6 = s_dt[t + 6], d7 = s_dt[t + 7];
            y = sde_step(y, d0.x, d0.y, z0, fw1, fb1, fw2, fD, gw1, gb1, gw2, gD);
            y = sde_step(y, d1.x, d1.y, z1, fw1, fb1, fw2, fD, gw1, gb1, gw2, gD);
            y = sde_step(y, d2.x, d2.y, z2, fw1, fb1, fw2, fD, gw1, gb1, gw2, gD);
            y = sde_step(y, d3.x, d3.y, z3, fw1, fb1, fw2, fD, gw1, gb1, gw2, gD);
            y = sde_step(y, d4.x, d4.y, z4, fw1, fb1, fw2, fD, gw1, gb1, gw2, gD);
            y = sde_step(y, d5.x, d5.y, z5, fw1, fb1, fw2, fD, gw1, gb1, gw2, gD);
            y = sde_step(y, d6.x, d6.y, z6, fw1, fb1, fw2, fD, gw1, gb1, gw2, gD);
            y = sde_step(y, d7.x, d7.y, z7, fw1, fb1, fw2, fD, gw1, gb1, gw2, gD);
        }
        for (t += 8; t < NSTEP; ++t) {
            float z = np[(size_t)t * NPATH];
            float2 d = s_dt[t];
            y = sde_step(y, d.x, d.y, z, fw1, fb1, fw2, fD, gw1, gb1, gw2, gD);
        }
    } else {
        // ---- general path: loop over active terms (correctness fallback) ----
        for (int t = 0; t < NSTEP; ++t) {
            float z = noise[(size_t)t * NPATH + i];
            float2 d = s_dt[t];
            float af = fD;
            for (int k = 0; k < nf; ++k) {
                float e = fexp2(fmaf(s_w1p[0][k], y, s_b1p[0][k]));
                float r = frcp(e + 1.0f);
                af = fmaf(s_w2t[0][k], r, af);
            }
            float fv = fmaf(-2.0f, frcp(fexp2(af) + 1.0f), 1.0f);
            float ag = gD;
            for (int k = 0; k < ng; ++k) {
                float e = fexp2(fmaf(s_w1p[1][k], y, s_b1p[1][k]));
                float r = frcp(e + 1.0f);
                ag = fmaf(s_w2t[1][k], r, ag);
            }
            float gv = fmaf(-2.0f, frcp(fexp2(ag) + 1.0f), 1.0f);
            y = fmaf(fv, d.x, y);
            y = fmaf(gv, d.y * z, y);
        }
    }

    out[i] = logf(y / yinit);
}

extern "C" void kernel_launch(void* const* d_in, const int* in_sizes, int n_in,
                              void* d_out, int out_size, void* d_ws, size_t ws_size,
                              hipStream_t stream)
{
    const float* y0    = (const float*)d_in[0];
    const float* times = (const float*)d_in[1];
    const float* noise = (const float*)d_in[2];
    const float* f1_w  = (const float*)d_in[3];
    const float* f1_b  = (const float*)d_in[4];
    const float* f2_w  = (const float*)d_in[5];
    const float* f2_b  = (const float*)d_in[6];
    const float* g1_w  = (const float*)d_in[7];
    const float* g1_b  = (const float*)d_in[8];
    const float* g2_w  = (const float*)d_in[9];
    const float* g2_b  = (const float*)d_in[10];
    float* out = (float*)d_out;

    deepsde_kernel<<<NPATH / BLOCK, BLOCK, 0, stream>>>(
        y0, times, noise,
        f1_w, f1_b, f2_w, f2_b,
        g1_w, g1_b, g2_w, g2_b,
        out);
}